// Round 17
// baseline (854.981 us; speedup 1.0000x reference)
//
#include <hip/hip_runtime.h>
#include <hip/hip_bf16.h>
#include <cstddef>

__device__ __forceinline__ unsigned short f2bf(float f) {
    union { float f; unsigned int u; } v; v.f = f;
    unsigned int r = (v.u + 0x7fffu + ((v.u >> 16) & 1u)) >> 16;   // RNE
    return (unsigned short)r;
}

typedef __bf16    bf16x8 __attribute__((ext_vector_type(8)));
typedef float     f32x4  __attribute__((ext_vector_type(4)));
typedef _Float16  f16x8  __attribute__((ext_vector_type(8)));

#define SPLIT_SCALE 2.44140625e-4f   // 2^-12

typedef const __attribute__((address_space(1))) void cglb_t;
typedef __attribute__((address_space(3))) void lds_t;

// fp32 -> fp16 (hi, lo*4096) split: hi + 2^-12*lo == v to ~2^-22 relative.
__device__ __forceinline__ void fsplit(float v, _Float16& hi, _Float16& lo) {
    hi = (_Float16)v;
    lo = (_Float16)((v - (float)hi) * 4096.0f);
}

// chunk swizzle for linear [row][32-elem] LDS tiles (row = 4 x 16B chunks):
// physical chunk = logical chunk ^ swz4(row). Involution; uniform bank-quads.
__device__ __forceinline__ int swz4(int r) { return (r & 3) ^ ((r >> 2) & 3); }

// ---------------------------------------------------------------------------
// Split-fp16 MFMA GEMM v7 (h1): global_load_lds staging for A AND B
// (hi/lo planes), swizzled linear LDS, double-buffered, one barrier per
// K-step. Staged a FULL K-step ahead (r14 lesson).
// ---------------------------------------------------------------------------
template<int K>
__global__ __launch_bounds__(256, 3)
void gemm_split7(const _Float16* __restrict__ Ahi, const _Float16* __restrict__ Alo,
                 const _Float16* __restrict__ Bhi, const _Float16* __restrict__ Blo,
                 const float* __restrict__ bias,
                 _Float16* __restrict__ Chi, _Float16* __restrict__ Clo,
                 int M, int N)
{
    constexpr int BK = 32;
    constexpr int NS = K / BK;

    __shared__ alignas(16) _Float16 SA[2][2][128 * 32];
    __shared__ alignas(16) _Float16 SB[2][2][64 * 32];

    const int tid  = threadIdx.x;
    const int lane = tid & 63;
    const int w    = tid >> 6;

    int bx = blockIdx.x, by = blockIdx.y;
    {
        const int gx = gridDim.x, nwg = gx * gridDim.y;
        if ((nwg & 7) == 0) {
            int d = bx + by * gx;
            int L = (d & 7) * (nwg >> 3) + (d >> 3);
            bx = L % gx; by = L / gx;
        }
    }
    const int bm = by * 128;
    const int bn = bx * 64;

    f32x4 acc0[2][4], acc1[2][4];
#pragma unroll
    for (int m = 0; m < 2; ++m)
#pragma unroll
        for (int n = 0; n < 4; ++n) {
            acc0[m][n] = (f32x4){0.f, 0.f, 0.f, 0.f};
            acc1[m][n] = (f32x4){0.f, 0.f, 0.f, 0.f};
        }

    auto stage = [&](int buf, int k0) {
#pragma unroll
        for (int pl = 0; pl < 2; ++pl) {
            const _Float16* src = pl ? Alo : Ahi;
#pragma unroll
            for (int j = 0; j < 2; ++j) {
                const int p16 = (w * 2 + j) * 64 + lane;
                const int r   = p16 >> 2;
                const int c   = (p16 & 3) ^ swz4(r);
                const _Float16* g = src + (size_t)(bm + r) * K + k0 + c * 8;
                __builtin_amdgcn_global_load_lds((cglb_t*)g,
                    (lds_t*)&SA[buf][pl][p16 * 8], 16, 0, 0);
            }
            const _Float16* srcB = pl ? Blo : Bhi;
            const int p16b = w * 64 + lane;
            const int rb   = p16b >> 2;
            const int cb   = (p16b & 3) ^ swz4(rb);
            const _Float16* gB = srcB + (size_t)(bn + rb) * K + k0 + cb * 8;
            __builtin_amdgcn_global_load_lds((cglb_t*)gB,
                (lds_t*)&SB[buf][pl][p16b * 8], 16, 0, 0);
        }
    };

    stage(0, 0);
    __syncthreads();

    const int g   = lane >> 4;
    const int r15 = lane & 15;

#pragma unroll
    for (int s = 0; s < NS; ++s) {
        const int p = s & 1;
        if (s + 1 < NS) stage(p ^ 1, (s + 1) * BK);

        f16x8 ah[2], al[2];
#pragma unroll
        for (int m = 0; m < 2; ++m) {
            const int R = w * 32 + m * 16 + r15;
            const int a16 = R * 4 + (g ^ swz4(R));
            ah[m] = *reinterpret_cast<const f16x8*>(&SA[p][0][a16 * 8]);
            al[m] = *reinterpret_cast<const f16x8*>(&SA[p][1][a16 * 8]);
        }
#pragma unroll
        for (int n = 0; n < 4; ++n) {
            const int rB = n * 16 + r15;
            const int b16 = rB * 4 + (g ^ swz4(rB));
            const f16x8 bh = *reinterpret_cast<const f16x8*>(&SB[p][0][b16 * 8]);
            const f16x8 bl = *reinterpret_cast<const f16x8*>(&SB[p][1][b16 * 8]);
#pragma unroll
            for (int m = 0; m < 2; ++m)
                acc0[m][n] = __builtin_amdgcn_mfma_f32_16x16x32_f16(
                    ah[m], bh, acc0[m][n], 0, 0, 0);
#pragma unroll
            for (int m = 0; m < 2; ++m)
                acc1[m][n] = __builtin_amdgcn_mfma_f32_16x16x32_f16(
                    ah[m], bl, acc1[m][n], 0, 0, 0);
#pragma unroll
            for (int m = 0; m < 2; ++m)
                acc1[m][n] = __builtin_amdgcn_mfma_f32_16x16x32_f16(
                    al[m], bh, acc1[m][n], 0, 0, 0);
        }
        __syncthreads();
    }

#pragma unroll
    for (int m = 0; m < 2; ++m)
#pragma unroll
        for (int n = 0; n < 4; ++n) {
            const int col = bn + n * 16 + r15;
            const float bv = bias[col];
#pragma unroll
            for (int q = 0; q < 4; ++q) {
                const int row = bm + w * 32 + m * 16 + (lane >> 4) * 4 + q;
                float v = acc0[m][n][q] + SPLIT_SCALE * acc1[m][n][q] + bv;
                v = fmaxf(v, 0.f);
                _Float16 hi, lo; fsplit(v, hi, lo);
                Chi[(size_t)row * N + col] = hi;
                Clo[(size_t)row * N + col] = lo;
            }
        }
}

// ---------------------------------------------------------------------------
// Split-fp16 MFMA GEMM v7f (h0): A = fp32 X, reg-staged + fsplit + ds_write
// into the SAME swizzled layout (thread writes physical chunk p16 with data
// from logical column (p16&3)^swz4(r) -> read side identical to split7).
// Issue-early / write-late; B DMA-staged; one barrier per K-step.
// ---------------------------------------------------------------------------
__global__ __launch_bounds__(256, 3)
void gemm_split7f(const float* __restrict__ Af,
                  const _Float16* __restrict__ Bhi, const _Float16* __restrict__ Blo,
                  const float* __restrict__ bias,
                  _Float16* __restrict__ Chi, _Float16* __restrict__ Clo,
                  int M, int N)
{
    constexpr int K  = 256;
    constexpr int BK = 32;
    constexpr int NS = K / BK;

    __shared__ alignas(16) _Float16 SA[2][2][128 * 32];
    __shared__ alignas(16) _Float16 SB[2][2][64 * 32];

    const int tid  = threadIdx.x;
    const int lane = tid & 63;
    const int w    = tid >> 6;

    int bx = blockIdx.x, by = blockIdx.y;
    {
        const int gx = gridDim.x, nwg = gx * gridDim.y;
        if ((nwg & 7) == 0) {
            int d = bx + by * gx;
            int L = (d & 7) * (nwg >> 3) + (d >> 3);
            bx = L % gx; by = L / gx;
        }
    }
    const int bm = by * 128;
    const int bn = bx * 64;

    f32x4 acc0[2][4], acc1[2][4];
#pragma unroll
    for (int m = 0; m < 2; ++m)
#pragma unroll
        for (int n = 0; n < 4; ++n) {
            acc0[m][n] = (f32x4){0.f, 0.f, 0.f, 0.f};
            acc1[m][n] = (f32x4){0.f, 0.f, 0.f, 0.f};
        }

    // A staging: thread owns physical chunks p16 = tid*2, tid*2+1
    float4 ra[2][2];                              // [chunk][half] fp32 regs
    auto loadA = [&](int k0) {
#pragma unroll
        for (int j = 0; j < 2; ++j) {
            const int p16 = tid * 2 + j;
            const int r   = p16 >> 2;
            const int c   = (p16 & 3) ^ swz4(r);
            const float* g = Af + (size_t)(bm + r) * K + k0 + c * 8;
            ra[j][0] = *reinterpret_cast<const float4*>(g);
            ra[j][1] = *reinterpret_cast<const float4*>(g + 4);
        }
    };
    auto writeA = [&](int buf) {
#pragma unroll
        for (int j = 0; j < 2; ++j) {
            const int p16 = tid * 2 + j;
            float vv[8] = {ra[j][0].x, ra[j][0].y, ra[j][0].z, ra[j][0].w,
                           ra[j][1].x, ra[j][1].y, ra[j][1].z, ra[j][1].w};
            f16x8 hh, ll;
#pragma unroll
            for (int e = 0; e < 8; ++e) {
                _Float16 hi, lo; fsplit(vv[e], hi, lo);
                hh[e] = hi; ll[e] = lo;
            }
            *reinterpret_cast<f16x8*>(&SA[buf][0][p16 * 8]) = hh;
            *reinterpret_cast<f16x8*>(&SA[buf][1][p16 * 8]) = ll;
        }
    };
    auto stageB = [&](int buf, int k0) {
#pragma unroll
        for (int pl = 0; pl < 2; ++pl) {
            const _Float16* srcB = pl ? Blo : Bhi;
            const int p16b = w * 64 + lane;
            const int rb   = p16b >> 2;
            const int cb   = (p16b & 3) ^ swz4(rb);
            const _Float16* gB = srcB + (size_t)(bn + rb) * K + k0 + cb * 8;
            __builtin_amdgcn_global_load_lds((cglb_t*)gB,
                (lds_t*)&SB[buf][pl][p16b * 8], 16, 0, 0);
        }
    };

    loadA(0);
    stageB(0, 0);
    writeA(0);
    __syncthreads();

    const int g   = lane >> 4;
    const int r15 = lane & 15;

#pragma unroll
    for (int s = 0; s < NS; ++s) {
        const int p = s & 1;
        if (s + 1 < NS) {                        // issue next-step loads EARLY
            stageB(p ^ 1, (s + 1) * BK);
            loadA((s + 1) * BK);
        }

        f16x8 ah[2], al[2];
#pragma unroll
        for (int m = 0; m < 2; ++m) {
            const int R = w * 32 + m * 16 + r15;
            const int a16 = R * 4 + (g ^ swz4(R));
            ah[m] = *reinterpret_cast<const f16x8*>(&SA[p][0][a16 * 8]);
            al[m] = *reinterpret_cast<const f16x8*>(&SA[p][1][a16 * 8]);
        }
#pragma unroll
        for (int n = 0; n < 4; ++n) {
            const int rB = n * 16 + r15;
            const int b16 = rB * 4 + (g ^ swz4(rB));
            const f16x8 bh = *reinterpret_cast<const f16x8*>(&SB[p][0][b16 * 8]);
            const f16x8 bl = *reinterpret_cast<const f16x8*>(&SB[p][1][b16 * 8]);
#pragma unroll
            for (int m = 0; m < 2; ++m)
                acc0[m][n] = __builtin_amdgcn_mfma_f32_16x16x32_f16(
                    ah[m], bh, acc0[m][n], 0, 0, 0);
#pragma unroll
            for (int m = 0; m < 2; ++m)
                acc1[m][n] = __builtin_amdgcn_mfma_f32_16x16x32_f16(
                    ah[m], bl, acc1[m][n], 0, 0, 0);
#pragma unroll
            for (int m = 0; m < 2; ++m)
                acc1[m][n] = __builtin_amdgcn_mfma_f32_16x16x32_f16(
                    al[m], bh, acc1[m][n], 0, 0, 0);
        }
        if (s + 1 < NS) writeA(p ^ 1);           // write-late into other buffer
        __syncthreads();
    }

#pragma unroll
    for (int m = 0; m < 2; ++m)
#pragma unroll
        for (int n = 0; n < 4; ++n) {
            const int col = bn + n * 16 + r15;
            const float bv = bias[col];
#pragma unroll
            for (int q = 0; q < 4; ++q) {
                const int row = bm + w * 32 + m * 16 + (lane >> 4) * 4 + q;
                float v = acc0[m][n][q] + SPLIT_SCALE * acc1[m][n][q] + bv;
                v = fmaxf(v, 0.f);
                _Float16 hi, lo; fsplit(v, hi, lo);
                Chi[(size_t)row * N + col] = hi;
                Clo[(size_t)row * N + col] = lo;
            }
        }
}

// ---------------------------------------------------------------------------
// bf16 MFMA GEMM v7 (decoder): DMA-staged swizzled structure, 128x128 tile,
// BK=32, double-buffered, one barrier per K-step. 32KB LDS.
// ---------------------------------------------------------------------------
template<bool RELU, bool OUT_BF16>
__global__ __launch_bounds__(256, 3)
void gemm_bt7(const unsigned short* __restrict__ A,
              const unsigned short* __restrict__ Bt,
              const float* __restrict__ bias,
              void* __restrict__ Cv, int M, int N, int K)
{
    constexpr int BK = 32;

    __shared__ alignas(16) unsigned short SA[2][128 * 32];
    __shared__ alignas(16) unsigned short SB[2][128 * 32];

    const int tid  = threadIdx.x;
    const int lane = tid & 63;
    const int w    = tid >> 6;
    const int wr   = (w >> 1) * 64;
    const int wc   = (w & 1) * 64;

    int bx = blockIdx.x, by = blockIdx.y;
    {
        const int gx = gridDim.x, nwg = gx * gridDim.y;
        if ((nwg & 7) == 0) {
            int d = bx + by * gx;
            int L = (d & 7) * (nwg >> 3) + (d >> 3);
            bx = L % gx; by = L / gx;
        }
    }
    const int bm = by * 128;
    const int bn = bx * 128;

    f32x4 acc[4][4];
#pragma unroll
    for (int m = 0; m < 4; ++m)
#pragma unroll
        for (int n = 0; n < 4; ++n) acc[m][n] = (f32x4){0.f, 0.f, 0.f, 0.f};

    auto stage = [&](int buf, int k0) {
#pragma unroll
        for (int j = 0; j < 2; ++j) {
            const int p16 = (w * 2 + j) * 64 + lane;
            const int r   = p16 >> 2;
            const int c   = (p16 & 3) ^ swz4(r);
            const unsigned short* gA = A + (size_t)(bm + r) * K + k0 + c * 8;
            __builtin_amdgcn_global_load_lds((cglb_t*)gA,
                (lds_t*)&SA[buf][p16 * 8], 16, 0, 0);
            const unsigned short* gB = Bt + (size_t)(bn + r) * K + k0 + c * 8;
            __builtin_amdgcn_global_load_lds((cglb_t*)gB,
                (lds_t*)&SB[buf][p16 * 8], 16, 0, 0);
        }
    };

    stage(0, 0);
    __syncthreads();

    const int g   = lane >> 4;
    const int r15 = lane & 15;
    const int NS  = K / BK;

    for (int s = 0; s < NS; ++s) {
        const int p = s & 1;
        if (s + 1 < NS) stage(p ^ 1, (s + 1) * BK);

        bf16x8 af[4], bf[4];
#pragma unroll
        for (int m = 0; m < 4; ++m) {
            const int R = wr + m * 16 + r15;
            const int a16 = R * 4 + (g ^ swz4(R));
            af[m] = *reinterpret_cast<const bf16x8*>(&SA[p][a16 * 8]);
        }
#pragma unroll
        for (int n = 0; n < 4; ++n) {
            const int RB = wc + n * 16 + r15;
            const int b16 = RB * 4 + (g ^ swz4(RB));
            bf[n] = *reinterpret_cast<const bf16x8*>(&SB[p][b16 * 8]);
        }
#pragma unroll
        for (int m = 0; m < 4; ++m)
#pragma unroll
            for (int n = 0; n < 4; ++n)
                acc[m][n] = __builtin_amdgcn_mfma_f32_16x16x32_bf16(
                    af[m], bf[n], acc[m][n], 0, 0, 0);
        __syncthreads();
    }

#pragma unroll
    for (int m = 0; m < 4; ++m)
#pragma unroll
        for (int n = 0; n < 4; ++n) {
            const int col = bn + wc + n * 16 + r15;
            const float bv = bias[col];
#pragma unroll
            for (int q = 0; q < 4; ++q) {
                const int row = bm + wr + m * 16 + (lane >> 4) * 4 + q;
                float v = acc[m][n][q] + bv;
                if (RELU) v = fmaxf(v, 0.f);
                if (OUT_BF16)
                    reinterpret_cast<unsigned short*>(Cv)[(size_t)row * N + col] = f2bf(v);
                else
                    reinterpret_cast<float*>(Cv)[(size_t)row * N + col] = v;
            }
        }
}

// ---------------------------------------------------------------------------
// z_e GEMM via split-fp16 MFMA: ze[M,64] = h1 @ W2 + b2, fp32 accumulation.
// ---------------------------------------------------------------------------
__global__ __launch_bounds__(256)
void gemm_ze_mfma(const _Float16* __restrict__ Ahi, const _Float16* __restrict__ Alo,
                  const _Float16* __restrict__ Bhi, const _Float16* __restrict__ Blo,
                  const float* __restrict__ bias, float* __restrict__ C, int M)
{
    constexpr int K = 512, N = 64;
    const int tid  = threadIdx.x;
    const int lane = tid & 63;
    const int w    = tid >> 6;
    const int wr   = (w >> 1) * 64;
    const int wc   = (w & 1) * 32;
    const int bm   = blockIdx.x * 128;

    f32x4 acc0[4][2], acc1[4][2];
#pragma unroll
    for (int m = 0; m < 4; ++m)
#pragma unroll
        for (int n = 0; n < 2; ++n) {
            acc0[m][n] = (f32x4){0.f, 0.f, 0.f, 0.f};
            acc1[m][n] = (f32x4){0.f, 0.f, 0.f, 0.f};
        }

    const int arow = bm + wr + (lane & 15);
    const int kgrp = (lane >> 4) * 8;

#pragma unroll
    for (int ks = 0; ks < K / 32; ++ks) {
        const int k0 = ks * 32 + kgrp;
        f16x8 ah[4], al[4];
#pragma unroll
        for (int m = 0; m < 4; ++m) {
            const size_t ga = (size_t)(arow + m * 16) * K + k0;
            ah[m] = *reinterpret_cast<const f16x8*>(Ahi + ga);
            al[m] = *reinterpret_cast<const f16x8*>(Alo + ga);
        }
#pragma unroll
        for (int n = 0; n < 2; ++n) {
            const size_t gb = (size_t)(wc + n * 16 + (lane & 15)) * K + k0;
            const f16x8 bh = *reinterpret_cast<const f16x8*>(Bhi + gb);
            const f16x8 bl = *reinterpret_cast<const f16x8*>(Blo + gb);
#pragma unroll
            for (int m = 0; m < 4; ++m)
                acc0[m][n] = __builtin_amdgcn_mfma_f32_16x16x32_f16(
                    ah[m], bh, acc0[m][n], 0, 0, 0);
#pragma unroll
            for (int m = 0; m < 4; ++m)
                acc1[m][n] = __builtin_amdgcn_mfma_f32_16x16x32_f16(
                    ah[m], bl, acc1[m][n], 0, 0, 0);
#pragma unroll
            for (int m = 0; m < 4; ++m)
                acc1[m][n] = __builtin_amdgcn_mfma_f32_16x16x32_f16(
                    al[m], bh, acc1[m][n], 0, 0, 0);
        }
    }

#pragma unroll
    for (int m = 0; m < 4; ++m)
#pragma unroll
        for (int n = 0; n < 2; ++n) {
            const int col = wc + n * 16 + (lane & 15);
            const float bv = bias[col];
#pragma unroll
            for (int q = 0; q < 4; ++q) {
                const int row = bm + wr + m * 16 + (lane >> 4) * 4 + q;
                C[(size_t)row * N + col] = acc0[m][n][q] + SPLIT_SCALE * acc1[m][n][q] + bv;
            }
        }
}

// ---------------------------------------------------------------------------
// VQ via MFMA: fp32 d2 filter -> candidate-only exact fp64 re-check.
// ---------------------------------------------------------------------------
#define VQ_EPS 1e-3f
__global__ __launch_bounds__(512)
void vq_mfma(const float* __restrict__ Z, const float* __restrict__ CB,
             const _Float16* __restrict__ Chi, const _Float16* __restrict__ Clo,
             float* __restrict__ OUT, unsigned short* __restrict__ ZQB)
{
    __shared__ float  ccf[256];
    __shared__ double ccd[256];
    __shared__ float  xxf[128];
    __shared__ double xxd[128];
    __shared__ float  redv[4][128];
    __shared__ int    redi[4][128];
    __shared__ float  bv1s[128];
    __shared__ int    bis[128];
    __shared__ int    cand[128][16];
    __shared__ int    ncand[128];
    __shared__ int    fullflag[128];
    __shared__ int    flaglist[128];
    __shared__ int    nflag;

    const int tid  = threadIdx.x;
    const int lane = tid & 63;
    const int w    = tid >> 6;
    const int wr   = (w >> 2) * 64;
    const int wc   = (w & 3) * 64;
    const int bm   = blockIdx.x * 128;

    if (tid == 0) nflag = 0;
    if (tid < 256) {
        const float4* c4 = reinterpret_cast<const float4*>(CB + (size_t)tid * 64);
        double cc = 0.0;
#pragma unroll
        for (int v = 0; v < 16; ++v) {
            float4 f = c4[v];
            cc = fma((double)f.x, (double)f.x, cc);
            cc = fma((double)f.y, (double)f.y, cc);
            cc = fma((double)f.z, (double)f.z, cc);
            cc = fma((double)f.w, (double)f.w, cc);
        }
        ccd[tid] = cc; ccf[tid] = (float)cc;
    }
    if (tid < 128) {
        const float4* z4 = reinterpret_cast<const float4*>(Z + (size_t)(bm + tid) * 64);
        double xx = 0.0;
#pragma unroll
        for (int v = 0; v < 16; ++v) {
            float4 f = z4[v];
            xx = fma((double)f.x, (double)f.x, xx);
            xx = fma((double)f.y, (double)f.y, xx);
            xx = fma((double)f.z, (double)f.z, xx);
            xx = fma((double)f.w, (double)f.w, xx);
        }
        xxd[tid] = xx; xxf[tid] = (float)xx;
        ncand[tid] = 0; fullflag[tid] = 0;
    }
    __syncthreads();

    f32x4 acc0[4][4], acc1[4][4];
#pragma unroll
    for (int m = 0; m < 4; ++m)
#pragma unroll
        for (int n = 0; n < 4; ++n) {
            acc0[m][n] = (f32x4){0.f, 0.f, 0.f, 0.f};
            acc1[m][n] = (f32x4){0.f, 0.f, 0.f, 0.f};
        }

    const int arow = bm + wr + (lane & 15);
    const int kgrp = (lane >> 4) * 8;

#pragma unroll
    for (int ks = 0; ks < 2; ++ks) {
        const int k0 = ks * 32 + kgrp;
        f16x8 ah[4], al[4];
#pragma unroll
        for (int m = 0; m < 4; ++m) {
            const float* src = Z + (size_t)(arow + m * 16) * 64 + k0;
            float4 v0 = *reinterpret_cast<const float4*>(src);
            float4 v1 = *reinterpret_cast<const float4*>(src + 4);
            float vv[8] = {v0.x, v0.y, v0.z, v0.w, v1.x, v1.y, v1.z, v1.w};
            f16x8 hh, ll;
#pragma unroll
            for (int j = 0; j < 8; ++j) {
                _Float16 hi, lo; fsplit(vv[j], hi, lo);
                hh[j] = hi; ll[j] = lo;
            }
            ah[m] = hh; al[m] = ll;
        }
#pragma unroll
        for (int n = 0; n < 4; ++n) {
            const size_t gb = (size_t)(wc + n * 16 + (lane & 15)) * 64 + k0;
            const f16x8 bh = *reinterpret_cast<const f16x8*>(Chi + gb);
            const f16x8 bl = *reinterpret_cast<const f16x8*>(Clo + gb);
#pragma unroll
            for (int m = 0; m < 4; ++m)
                acc0[m][n] = __builtin_amdgcn_mfma_f32_16x16x32_f16(
                    ah[m], bh, acc0[m][n], 0, 0, 0);
#pragma unroll
            for (int m = 0; m < 4; ++m)
                acc1[m][n] = __builtin_amdgcn_mfma_f32_16x16x32_f16(
                    ah[m], bl, acc1[m][n], 0, 0, 0);
#pragma unroll
            for (int m = 0; m < 4; ++m)
                acc1[m][n] = __builtin_amdgcn_mfma_f32_16x16x32_f16(
                    al[m], bh, acc1[m][n], 0, 0, 0);
        }
    }

#pragma unroll
    for (int m = 0; m < 4; ++m)
#pragma unroll
        for (int n = 0; n < 4; ++n) {
            const int col = wc + n * 16 + (lane & 15);
            const float cf = ccf[col];
#pragma unroll
            for (int q = 0; q < 4; ++q) {
                const int rl = wr + m * 16 + (lane >> 4) * 4 + q;
                float dot = acc0[m][n][q] + SPLIT_SCALE * acc1[m][n][q];
                acc0[m][n][q] = (xxf[rl] - 2.0f * dot) + cf;
            }
        }

    float bvr[4][4]; int bir[4][4];
#pragma unroll
    for (int m = 0; m < 4; ++m)
#pragma unroll
        for (int q = 0; q < 4; ++q) {
            float bv = 3.4e38f; int bi = 0;
#pragma unroll
            for (int n = 0; n < 4; ++n) {
                const int col = wc + n * 16 + (lane & 15);
                const float v = acc0[m][n][q];
                if (v < bv || (v == bv && col < bi)) { bv = v; bi = col; }
            }
            bvr[m][q] = bv; bir[m][q] = bi;
        }
#pragma unroll
    for (int mask = 1; mask < 16; mask <<= 1) {
#pragma unroll
        for (int m = 0; m < 4; ++m)
#pragma unroll
            for (int q = 0; q < 4; ++q) {
                float ov = __shfl_xor(bvr[m][q], mask);
                int   oi = __shfl_xor(bir[m][q], mask);
                if (ov < bvr[m][q] || (ov == bvr[m][q] && oi < bir[m][q])) {
                    bvr[m][q] = ov; bir[m][q] = oi;
                }
            }
    }
    if ((lane & 15) == 0) {
#pragma unroll
        for (int m = 0; m < 4; ++m)
#pragma unroll
            for (int q = 0; q < 4; ++q) {
                const int rl = wr + m * 16 + (lane >> 4) * 4 + q;
                redv[w & 3][rl] = bvr[m][q];
                redi[w & 3][rl] = bir[m][q];
            }
    }
    __syncthreads();

    if (tid < 128) {
        float bv = 3.4e38f; int bi = 0;
#pragma unroll
        for (int nw = 0; nw < 4; ++nw) {
            float v = redv[nw][tid];
            if (v < bv) { bv = v; bi = redi[nw][tid]; }
        }
        bv1s[tid] = bv; bis[tid] = bi;
    }
    __syncthreads();

#pragma unroll
    for (int m = 0; m < 4; ++m)
#pragma unroll
        for (int q = 0; q < 4; ++q) {
            const int rl = wr + m * 16 + (lane >> 4) * 4 + q;
            const float thr = bv1s[rl] + VQ_EPS;
#pragma unroll
            for (int n = 0; n < 4; ++n) {
                const int col = wc + n * 16 + (lane & 15);
                if (acc0[m][n][q] <= thr) {
                    int s = atomicAdd(&ncand[rl], 1);
                    if (s < 16) cand[rl][s] = col;
                    else        fullflag[rl] = 1;
                }
            }
        }
    __syncthreads();

    if (tid < 128) {
        const int nc_ = ncand[tid] < 16 ? ncand[tid] : 16;
        if (nc_ > 1 && !fullflag[tid]) {
            const float4* z4p = reinterpret_cast<const float4*>(Z + (size_t)(bm + tid) * 64);
            const double xx = xxd[tid];
            double best = 1.0e300; int bi = 256;
            for (int s = 0; s < nc_; ++s) {
                const int e = cand[tid][s];
                const float4* c4p = reinterpret_cast<const float4*>(CB + (size_t)e * 64);
                double dot = 0.0;
#pragma unroll
                for (int v = 0; v < 16; ++v) {
                    float4 zf = z4p[v], cf4 = c4p[v];
                    dot = fma((double)zf.x, (double)cf4.x, dot);
                    dot = fma((double)zf.y, (double)cf4.y, dot);
                    dot = fma((double)zf.z, (double)cf4.z, dot);
                    dot = fma((double)zf.w, (double)cf4.w, dot);
                }
                double d2x = (xx - 2.0 * dot) + ccd[e];
                if (d2x < best || (d2x == best && e < bi)) { best = d2x; bi = e; }
            }
            bis[tid] = bi;
        }
        if (fullflag[tid]) {
            int s = atomicAdd(&nflag, 1);
            flaglist[s] = tid;
        }
    }
    __syncthreads();

    for (int fi = w; fi < nflag; fi += 8) {
        const int rl = flaglist[fi];
        const float* zr = Z + (size_t)(bm + rl) * 64;
        const double xx = xxd[rl];
        double best = 1.0e300; int bi = 256;
#pragma unroll
        for (int j = 0; j < 4; ++j) {
            const int e = lane + j * 64;
            const float* c = CB + (size_t)e * 64;
            double dot = 0.0;
#pragma unroll
            for (int d = 0; d < 64; ++d)
                dot = fma((double)zr[d], (double)c[d], dot);
            double d2x = (xx - 2.0 * dot) + ccd[e];
            if (d2x < best || (d2x == best && e < bi)) { best = d2x; bi = e; }
        }
#pragma unroll
        for (int mask = 1; mask < 64; mask <<= 1) {
            double ov = __shfl_xor(best, mask);
            int    oi = __shfl_xor(bi, mask);
            if (ov < best || (ov == best && oi < bi)) { best = ov; bi = oi; }
        }
        if (lane == 0) bis[rl] = bi;
    }
    __syncthreads();

    {
        const int row  = tid >> 2;
        const int part = tid & 3;
        const int bi   = bis[row];
        const float4* src = reinterpret_cast<const float4*>(CB + (size_t)bi * 64) + part * 4;
        float* dst = OUT + (size_t)(bm + row) * 64 + part * 16;
        unsigned short* dq = ZQB + (size_t)(bm + row) * 64 + part * 16;
#pragma unroll
        for (int v = 0; v < 4; ++v) {
            float4 f = src[v];
            *reinterpret_cast<float4*>(dst + v * 4) = f;
            ushort4 qb = { f2bf(f.x), f2bf(f.y), f2bf(f.z), f2bf(f.w) };
            *reinterpret_cast<ushort4*>(dq + v * 4) = qb;
        }
    }
}

// ---------------------------------------------------------------------------
// small prep kernels
// ---------------------------------------------------------------------------
__global__ __launch_bounds__(256)
void transpose_bf16(const float* __restrict__ W, unsigned short* __restrict__ Wt,
                    int K, int N)
{
    int idx = blockIdx.x * 256 + threadIdx.x;
    if (idx >= K * N) return;
    int n = idx / K, k = idx % K;
    Wt[idx] = f2bf(W[(size_t)k * N + n]);
}

__global__ __launch_bounds__(256)
void transpose_split_f16(const float* __restrict__ W,
                         _Float16* __restrict__ Whi, _Float16* __restrict__ Wlo,
                         int K, int N)
{
    int idx = blockIdx.x * 256 + threadIdx.x;
    if (idx >= K * N) return;
    int n = idx / K, k = idx % K;
    _Float16 hi, lo; fsplit(W[(size_t)k * N + n], hi, lo);
    Whi[idx] = hi; Wlo[idx] = lo;
}

__global__ __launch_bounds__(256)
void split_flat_f16(const float* __restrict__ src,
                    _Float16* __restrict__ hi, _Float16* __restrict__ lo, int n)
{
    int i = blockIdx.x * 256 + threadIdx.x;
    if (i >= n) return;
    _Float16 h, l; fsplit(src[i], h, l);
    hi[i] = h; lo[i] = l;
}

// ---------------------------------------------------------------------------
extern "C" void kernel_launch(void* const* d_in, const int* in_sizes, int n_in,
                              void* d_out, int out_size, void* d_ws, size_t ws_size,
                              hipStream_t stream)
{
    const float* X  = (const float*)d_in[0];
    const float* W0 = (const float*)d_in[1];
    const float* b0 = (const float*)d_in[2];
    const float* W1 = (const float*)d_in[3];
    const float* b1 = (const float*)d_in[4];
    const float* W2 = (const float*)d_in[5];
    const float* b2 = (const float*)d_in[6];
    const float* CB = (const float*)d_in[7];
    const float* W3 = (const float*)d_in[8];
    const float* b3 = (const float*)d_in[9];
    const float* W4 = (const float*)d_in[10];
    const float* b4 = (const float*)d_in[11];
    const float* W5 = (const float*)d_in[12];
    const float* b5 = (const float*)d_in[13];

    const int D_in = 256, H = 512, R = 64, S = 512, NA = 8;
    const int Mtot = in_sizes[0] / D_in;          // 131072

    float* recon = (float*)d_out;
    float* ze    = recon + (size_t)(Mtot / NA) * S;
    float* remb  = ze + (size_t)Mtot * R;

    // ---- workspace: fixed weight planes + FULL-M zqb ----
    char* p = (char*)d_ws;
    _Float16* W0hi = (_Float16*)p;  p += (size_t)H * D_in * 2;
    _Float16* W0lo = (_Float16*)p;  p += (size_t)H * D_in * 2;
    _Float16* W1hi = (_Float16*)p;  p += (size_t)H * H * 2;
    _Float16* W1lo = (_Float16*)p;  p += (size_t)H * H * 2;
    _Float16* W2thi = (_Float16*)p; p += (size_t)R * H * 2;
    _Float16* W2tlo = (_Float16*)p; p += (size_t)R * H * 2;
    _Float16* CBhi = (_Float16*)p;  p += (size_t)256 * R * 2;
    _Float16* CBlo = (_Float16*)p;  p += (size_t)256 * R * 2;
    unsigned short* W3t = (unsigned short*)p;  p += (size_t)H * R * 2;
    unsigned short* W4t = (unsigned short*)p;  p += (size_t)H * (NA * H) * 2;
    unsigned short* W5t = (unsigned short*)p;  p += (size_t)S * H * 2;
    unsigned short* zqb = (unsigned short*)p;  p += (size_t)Mtot * R * 2;   // 16.8 MB
    size_t fixed = (size_t)(p - (char*)d_ws);
    fixed = (fixed + 255) & ~(size_t)255;

    // big region: encoder phase uses [regionA (h1) | regionB (h0)], each
    // rpc*2048 B; decoder phase reuses regionB as rec1b, regionA as rec2b.
    int nc = 1;
    while (nc < 128) {
        size_t rpcT = (size_t)Mtot / nc;
        if (fixed + rpcT * 4096 + 1024 <= ws_size) break;
        nc *= 2;
    }
    const int rpc = Mtot / nc;
    char* regionA = (char*)d_ws + fixed;                 // rpc*2048
    char* regionB = regionA + (size_t)rpc * 2048;        // rpc*2048

    _Float16* h1hi = (_Float16*)regionA;
    _Float16* h1lo = h1hi + (size_t)rpc * H;
    _Float16* h0hi = (_Float16*)regionB;
    _Float16* h0lo = h0hi + (size_t)rpc * H;

    // decoder chunking: rec1b needs Mdec*1024 B <= regionB (rpc*2048)
    int dc = (nc >= 2) ? nc / 2 : 1;
    const int Mdec = Mtot / dc;
    unsigned short* rec1b = (unsigned short*)regionB;
    unsigned short* rec2b = (unsigned short*)regionA;

    // ---- one-time weight prep ----
    transpose_split_f16<<<(H * D_in + 255) / 256, 256, 0, stream>>>(W0, W0hi, W0lo, D_in, H);
    transpose_split_f16<<<(H * H + 255) / 256, 256, 0, stream>>>(W1, W1hi, W1lo, H, H);
    transpose_split_f16<<<(H * R + 255) / 256, 256, 0, stream>>>(W2, W2thi, W2tlo, H, R);
    split_flat_f16<<<(256 * R + 255) / 256, 256, 0, stream>>>(CB, CBhi, CBlo, 256 * R);
    transpose_bf16<<<(H * R + 255) / 256, 256, 0, stream>>>(W3, W3t, R, H);
    transpose_bf16<<<(H * NA * H + 255) / 256, 256, 0, stream>>>(W4, W4t, NA * H, H);
    transpose_bf16<<<(S * H + 255) / 256, 256, 0, stream>>>(W5, W5t, H, S);

    // ---- encoder + VQ per chunk (zqb written for full M) ----
    for (int r0 = 0; r0 < Mtot; r0 += rpc) {
        // h0: fused X-split (reg-stage + fsplit + ds_write) + DMA-staged B
        gemm_split7f<<<dim3(H / 64, rpc / 128), 256, 0, stream>>>(
            X + (size_t)r0 * D_in, W0hi, W0lo, b0, h0hi, h0lo, rpc, H);
        // h1: fully DMA-staged split (known-good)
        gemm_split7<512><<<dim3(H / 64, rpc / 128), 256, 0, stream>>>(
            h0hi, h0lo, W1hi, W1lo, b1, h1hi, h1lo, rpc, H);
        gemm_ze_mfma<<<rpc / 128, 256, 0, stream>>>(
            h1hi, h1lo, W2thi, W2tlo, b2, ze + (size_t)r0 * R, rpc);
        vq_mfma<<<rpc / 128, 512, 0, stream>>>(
            ze + (size_t)r0 * R, CB, CBhi, CBlo,
            remb + (size_t)r0 * R, zqb + (size_t)r0 * R);
    }

    // ---- decoder over full M (or Mdec chunks), bigger grids ----
    for (int r0 = 0; r0 < Mtot; r0 += Mdec) {
        const int M6 = Mdec / NA;
        gemm_bt7<true, true><<<dim3(H / 128, Mdec / 128), 256, 0, stream>>>(
            zqb + (size_t)r0 * R, W3t, b3, rec1b, Mdec, H, R);
        gemm_bt7<true, true><<<dim3(H / 128, M6 / 128), 256, 0, stream>>>(
            rec1b, W4t, b4, rec2b, M6, H, NA * H);
        gemm_bt7<false, false><<<dim3(S / 128, M6 / 128), 256, 0, stream>>>(
            rec2b, W5t, b5, recon + (size_t)(r0 / NA) * S, M6, S, H);
    }
}

// Round 18
// 840.683 us; speedup vs baseline: 1.0170x; 1.0170x over previous
//
#include <hip/hip_runtime.h>
#include <hip/hip_bf16.h>
#include <cstddef>

__device__ __forceinline__ unsigned short f2bf(float f) {
    union { float f; unsigned int u; } v; v.f = f;
    unsigned int r = (v.u + 0x7fffu + ((v.u >> 16) & 1u)) >> 16;   // RNE
    return (unsigned short)r;
}

typedef __bf16    bf16x8 __attribute__((ext_vector_type(8)));
typedef float     f32x4  __attribute__((ext_vector_type(4)));
typedef _Float16  f16x8  __attribute__((ext_vector_type(8)));

#define SPLIT_SCALE 2.44140625e-4f   // 2^-12

typedef const __attribute__((address_space(1))) void cglb_t;
typedef __attribute__((address_space(3))) void lds_t;

// fp32 -> fp16 (hi, lo*4096) split: hi + 2^-12*lo == v to ~2^-22 relative.
__device__ __forceinline__ void fsplit(float v, _Float16& hi, _Float16& lo) {
    hi = (_Float16)v;
    lo = (_Float16)((v - (float)hi) * 4096.0f);
}

// chunk swizzle for linear [row][32-elem] LDS tiles (row = 4 x 16B chunks):
// physical chunk = logical chunk ^ swz4(row). Involution; uniform bank-quads.
__device__ __forceinline__ int swz4(int r) { return (r & 3) ^ ((r >> 2) & 3); }

// ---------------------------------------------------------------------------
// Split-fp16 MFMA GEMM v7 (h0 & h1): global_load_lds staging for A AND B
// (hi/lo planes), swizzled linear LDS, double-buffered, one barrier per
// K-step. Staged a FULL K-step ahead (r14 lesson: same-iteration L2 reads
// expose ~300cy per step and halve throughput).
// ---------------------------------------------------------------------------
template<int K>
__global__ __launch_bounds__(256, 3)
void gemm_split7(const _Float16* __restrict__ Ahi, const _Float16* __restrict__ Alo,
                 const _Float16* __restrict__ Bhi, const _Float16* __restrict__ Blo,
                 const float* __restrict__ bias,
                 _Float16* __restrict__ Chi, _Float16* __restrict__ Clo,
                 int M, int N)
{
    constexpr int BK = 32;
    constexpr int NS = K / BK;

    __shared__ alignas(16) _Float16 SA[2][2][128 * 32];
    __shared__ alignas(16) _Float16 SB[2][2][64 * 32];

    const int tid  = threadIdx.x;
    const int lane = tid & 63;
    const int w    = tid >> 6;

    int bx = blockIdx.x, by = blockIdx.y;
    {
        const int gx = gridDim.x, nwg = gx * gridDim.y;
        if ((nwg & 7) == 0) {
            int d = bx + by * gx;
            int L = (d & 7) * (nwg >> 3) + (d >> 3);
            bx = L % gx; by = L / gx;
        }
    }
    const int bm = by * 128;
    const int bn = bx * 64;

    f32x4 acc0[2][4], acc1[2][4];
#pragma unroll
    for (int m = 0; m < 2; ++m)
#pragma unroll
        for (int n = 0; n < 4; ++n) {
            acc0[m][n] = (f32x4){0.f, 0.f, 0.f, 0.f};
            acc1[m][n] = (f32x4){0.f, 0.f, 0.f, 0.f};
        }

    auto stage = [&](int buf, int k0) {
#pragma unroll
        for (int pl = 0; pl < 2; ++pl) {
            const _Float16* src = pl ? Alo : Ahi;
#pragma unroll
            for (int j = 0; j < 2; ++j) {
                const int p16 = (w * 2 + j) * 64 + lane;
                const int r   = p16 >> 2;
                const int c   = (p16 & 3) ^ swz4(r);
                const _Float16* g = src + (size_t)(bm + r) * K + k0 + c * 8;
                __builtin_amdgcn_global_load_lds((cglb_t*)g,
                    (lds_t*)&SA[buf][pl][p16 * 8], 16, 0, 0);
            }
            const _Float16* srcB = pl ? Blo : Bhi;
            const int p16b = w * 64 + lane;
            const int rb   = p16b >> 2;
            const int cb   = (p16b & 3) ^ swz4(rb);
            const _Float16* gB = srcB + (size_t)(bn + rb) * K + k0 + cb * 8;
            __builtin_amdgcn_global_load_lds((cglb_t*)gB,
                (lds_t*)&SB[buf][pl][p16b * 8], 16, 0, 0);
        }
    };

    stage(0, 0);
    __syncthreads();

    const int g   = lane >> 4;
    const int r15 = lane & 15;

#pragma unroll
    for (int s = 0; s < NS; ++s) {
        const int p = s & 1;
        if (s + 1 < NS) stage(p ^ 1, (s + 1) * BK);

        f16x8 ah[2], al[2];
#pragma unroll
        for (int m = 0; m < 2; ++m) {
            const int R = w * 32 + m * 16 + r15;
            const int a16 = R * 4 + (g ^ swz4(R));
            ah[m] = *reinterpret_cast<const f16x8*>(&SA[p][0][a16 * 8]);
            al[m] = *reinterpret_cast<const f16x8*>(&SA[p][1][a16 * 8]);
        }
#pragma unroll
        for (int n = 0; n < 4; ++n) {
            const int rB = n * 16 + r15;
            const int b16 = rB * 4 + (g ^ swz4(rB));
            const f16x8 bh = *reinterpret_cast<const f16x8*>(&SB[p][0][b16 * 8]);
            const f16x8 bl = *reinterpret_cast<const f16x8*>(&SB[p][1][b16 * 8]);
#pragma unroll
            for (int m = 0; m < 2; ++m)
                acc0[m][n] = __builtin_amdgcn_mfma_f32_16x16x32_f16(
                    ah[m], bh, acc0[m][n], 0, 0, 0);
#pragma unroll
            for (int m = 0; m < 2; ++m)
                acc1[m][n] = __builtin_amdgcn_mfma_f32_16x16x32_f16(
                    ah[m], bl, acc1[m][n], 0, 0, 0);
#pragma unroll
            for (int m = 0; m < 2; ++m)
                acc1[m][n] = __builtin_amdgcn_mfma_f32_16x16x32_f16(
                    al[m], bh, acc1[m][n], 0, 0, 0);
        }
        __syncthreads();
    }

#pragma unroll
    for (int m = 0; m < 2; ++m)
#pragma unroll
        for (int n = 0; n < 4; ++n) {
            const int col = bn + n * 16 + r15;
            const float bv = bias[col];
#pragma unroll
            for (int q = 0; q < 4; ++q) {
                const int row = bm + w * 32 + m * 16 + (lane >> 4) * 4 + q;
                float v = acc0[m][n][q] + SPLIT_SCALE * acc1[m][n][q] + bv;
                v = fmaxf(v, 0.f);
                _Float16 hi, lo; fsplit(v, hi, lo);
                Chi[(size_t)row * N + col] = hi;
                Clo[(size_t)row * N + col] = lo;
            }
        }
}

// ---------------------------------------------------------------------------
// bf16 MFMA GEMM v7 (decoder): DMA-staged swizzled structure, 128x128 tile,
// BK=32, double-buffered, one barrier per K-step. 32KB LDS.
// ---------------------------------------------------------------------------
template<bool RELU, bool OUT_BF16>
__global__ __launch_bounds__(256, 3)
void gemm_bt7(const unsigned short* __restrict__ A,
              const unsigned short* __restrict__ Bt,
              const float* __restrict__ bias,
              void* __restrict__ Cv, int M, int N, int K)
{
    constexpr int BK = 32;

    __shared__ alignas(16) unsigned short SA[2][128 * 32];
    __shared__ alignas(16) unsigned short SB[2][128 * 32];

    const int tid  = threadIdx.x;
    const int lane = tid & 63;
    const int w    = tid >> 6;
    const int wr   = (w >> 1) * 64;
    const int wc   = (w & 1) * 64;

    int bx = blockIdx.x, by = blockIdx.y;
    {
        const int gx = gridDim.x, nwg = gx * gridDim.y;
        if ((nwg & 7) == 0) {
            int d = bx + by * gx;
            int L = (d & 7) * (nwg >> 3) + (d >> 3);
            bx = L % gx; by = L / gx;
        }
    }
    const int bm = by * 128;
    const int bn = bx * 128;

    f32x4 acc[4][4];
#pragma unroll
    for (int m = 0; m < 4; ++m)
#pragma unroll
        for (int n = 0; n < 4; ++n) acc[m][n] = (f32x4){0.f, 0.f, 0.f, 0.f};

    auto stage = [&](int buf, int k0) {
#pragma unroll
        for (int j = 0; j < 2; ++j) {
            const int p16 = (w * 2 + j) * 64 + lane;
            const int r   = p16 >> 2;
            const int c   = (p16 & 3) ^ swz4(r);
            const unsigned short* gA = A + (size_t)(bm + r) * K + k0 + c * 8;
            __builtin_amdgcn_global_load_lds((cglb_t*)gA,
                (lds_t*)&SA[buf][p16 * 8], 16, 0, 0);
            const unsigned short* gB = Bt + (size_t)(bn + r) * K + k0 + c * 8;
            __builtin_amdgcn_global_load_lds((cglb_t*)gB,
                (lds_t*)&SB[buf][p16 * 8], 16, 0, 0);
        }
    };

    stage(0, 0);
    __syncthreads();

    const int g   = lane >> 4;
    const int r15 = lane & 15;
    const int NS  = K / BK;

    for (int s = 0; s < NS; ++s) {
        const int p = s & 1;
        if (s + 1 < NS) stage(p ^ 1, (s + 1) * BK);

        bf16x8 af[4], bf[4];
#pragma unroll
        for (int m = 0; m < 4; ++m) {
            const int R = wr + m * 16 + r15;
            const int a16 = R * 4 + (g ^ swz4(R));
            af[m] = *reinterpret_cast<const bf16x8*>(&SA[p][a16 * 8]);
        }
#pragma unroll
        for (int n = 0; n < 4; ++n) {
            const int RB = wc + n * 16 + r15;
            const int b16 = RB * 4 + (g ^ swz4(RB));
            bf[n] = *reinterpret_cast<const bf16x8*>(&SB[p][b16 * 8]);
        }
#pragma unroll
        for (int m = 0; m < 4; ++m)
#pragma unroll
            for (int n = 0; n < 4; ++n)
                acc[m][n] = __builtin_amdgcn_mfma_f32_16x16x32_bf16(
                    af[m], bf[n], acc[m][n], 0, 0, 0);
        __syncthreads();
    }

#pragma unroll
    for (int m = 0; m < 4; ++m)
#pragma unroll
        for (int n = 0; n < 4; ++n) {
            const int col = bn + wc + n * 16 + r15;
            const float bv = bias[col];
#pragma unroll
            for (int q = 0; q < 4; ++q) {
                const int row = bm + wr + m * 16 + (lane >> 4) * 4 + q;
                float v = acc[m][n][q] + bv;
                if (RELU) v = fmaxf(v, 0.f);
                if (OUT_BF16)
                    reinterpret_cast<unsigned short*>(Cv)[(size_t)row * N + col] = f2bf(v);
                else
                    reinterpret_cast<float*>(Cv)[(size_t)row * N + col] = v;
            }
        }
}

// ---------------------------------------------------------------------------
// z_e GEMM via split-fp16 MFMA: ze[M,64] = h1 @ W2 + b2, fp32 accumulation.
// ---------------------------------------------------------------------------
__global__ __launch_bounds__(256)
void gemm_ze_mfma(const _Float16* __restrict__ Ahi, const _Float16* __restrict__ Alo,
                  const _Float16* __restrict__ Bhi, const _Float16* __restrict__ Blo,
                  const float* __restrict__ bias, float* __restrict__ C, int M)
{
    constexpr int K = 512, N = 64;
    const int tid  = threadIdx.x;
    const int lane = tid & 63;
    const int w    = tid >> 6;
    const int wr   = (w >> 1) * 64;
    const int wc   = (w & 1) * 32;
    const int bm   = blockIdx.x * 128;

    f32x4 acc0[4][2], acc1[4][2];
#pragma unroll
    for (int m = 0; m < 4; ++m)
#pragma unroll
        for (int n = 0; n < 2; ++n) {
            acc0[m][n] = (f32x4){0.f, 0.f, 0.f, 0.f};
            acc1[m][n] = (f32x4){0.f, 0.f, 0.f, 0.f};
        }

    const int arow = bm + wr + (lane & 15);
    const int kgrp = (lane >> 4) * 8;

#pragma unroll
    for (int ks = 0; ks < K / 32; ++ks) {
        const int k0 = ks * 32 + kgrp;
        f16x8 ah[4], al[4];
#pragma unroll
        for (int m = 0; m < 4; ++m) {
            const size_t ga = (size_t)(arow + m * 16) * K + k0;
            ah[m] = *reinterpret_cast<const f16x8*>(Ahi + ga);
            al[m] = *reinterpret_cast<const f16x8*>(Alo + ga);
        }
#pragma unroll
        for (int n = 0; n < 2; ++n) {
            const size_t gb = (size_t)(wc + n * 16 + (lane & 15)) * K + k0;
            const f16x8 bh = *reinterpret_cast<const f16x8*>(Bhi + gb);
            const f16x8 bl = *reinterpret_cast<const f16x8*>(Blo + gb);
#pragma unroll
            for (int m = 0; m < 4; ++m)
                acc0[m][n] = __builtin_amdgcn_mfma_f32_16x16x32_f16(
                    ah[m], bh, acc0[m][n], 0, 0, 0);
#pragma unroll
            for (int m = 0; m < 4; ++m)
                acc1[m][n] = __builtin_amdgcn_mfma_f32_16x16x32_f16(
                    ah[m], bl, acc1[m][n], 0, 0, 0);
#pragma unroll
            for (int m = 0; m < 4; ++m)
                acc1[m][n] = __builtin_amdgcn_mfma_f32_16x16x32_f16(
                    al[m], bh, acc1[m][n], 0, 0, 0);
        }
    }

#pragma unroll
    for (int m = 0; m < 4; ++m)
#pragma unroll
        for (int n = 0; n < 2; ++n) {
            const int col = wc + n * 16 + (lane & 15);
            const float bv = bias[col];
#pragma unroll
            for (int q = 0; q < 4; ++q) {
                const int row = bm + wr + m * 16 + (lane >> 4) * 4 + q;
                C[(size_t)row * N + col] = acc0[m][n][q] + SPLIT_SCALE * acc1[m][n][q] + bv;
            }
        }
}

// ---------------------------------------------------------------------------
// VQ via MFMA: fp32 d2 filter -> candidate-only exact fp64 re-check.
// ---------------------------------------------------------------------------
#define VQ_EPS 1e-3f
__global__ __launch_bounds__(512)
void vq_mfma(const float* __restrict__ Z, const float* __restrict__ CB,
             const _Float16* __restrict__ Chi, const _Float16* __restrict__ Clo,
             float* __restrict__ OUT, unsigned short* __restrict__ ZQB)
{
    __shared__ float  ccf[256];
    __shared__ double ccd[256];
    __shared__ float  xxf[128];
    __shared__ double xxd[128];
    __shared__ float  redv[4][128];
    __shared__ int    redi[4][128];
    __shared__ float  bv1s[128];
    __shared__ int    bis[128];
    __shared__ int    cand[128][16];
    __shared__ int    ncand[128];
    __shared__ int    fullflag[128];
    __shared__ int    flaglist[128];
    __shared__ int    nflag;

    const int tid  = threadIdx.x;
    const int lane = tid & 63;
    const int w    = tid >> 6;
    const int wr   = (w >> 2) * 64;
    const int wc   = (w & 3) * 64;
    const int bm   = blockIdx.x * 128;

    if (tid == 0) nflag = 0;
    if (tid < 256) {
        const float4* c4 = reinterpret_cast<const float4*>(CB + (size_t)tid * 64);
        double cc = 0.0;
#pragma unroll
        for (int v = 0; v < 16; ++v) {
            float4 f = c4[v];
            cc = fma((double)f.x, (double)f.x, cc);
            cc = fma((double)f.y, (double)f.y, cc);
            cc = fma((double)f.z, (double)f.z, cc);
            cc = fma((double)f.w, (double)f.w, cc);
        }
        ccd[tid] = cc; ccf[tid] = (float)cc;
    }
    if (tid < 128) {
        const float4* z4 = reinterpret_cast<const float4*>(Z + (size_t)(bm + tid) * 64);
        double xx = 0.0;
#pragma unroll
        for (int v = 0; v < 16; ++v) {
            float4 f = z4[v];
            xx = fma((double)f.x, (double)f.x, xx);
            xx = fma((double)f.y, (double)f.y, xx);
            xx = fma((double)f.z, (double)f.z, xx);
            xx = fma((double)f.w, (double)f.w, xx);
        }
        xxd[tid] = xx; xxf[tid] = (float)xx;
        ncand[tid] = 0; fullflag[tid] = 0;
    }
    __syncthreads();

    f32x4 acc0[4][4], acc1[4][4];
#pragma unroll
    for (int m = 0; m < 4; ++m)
#pragma unroll
        for (int n = 0; n < 4; ++n) {
            acc0[m][n] = (f32x4){0.f, 0.f, 0.f, 0.f};
            acc1[m][n] = (f32x4){0.f, 0.f, 0.f, 0.f};
        }

    const int arow = bm + wr + (lane & 15);
    const int kgrp = (lane >> 4) * 8;

#pragma unroll
    for (int ks = 0; ks < 2; ++ks) {
        const int k0 = ks * 32 + kgrp;
        f16x8 ah[4], al[4];
#pragma unroll
        for (int m = 0; m < 4; ++m) {
            const float* src = Z + (size_t)(arow + m * 16) * 64 + k0;
            float4 v0 = *reinterpret_cast<const float4*>(src);
            float4 v1 = *reinterpret_cast<const float4*>(src + 4);
            float vv[8] = {v0.x, v0.y, v0.z, v0.w, v1.x, v1.y, v1.z, v1.w};
            f16x8 hh, ll;
#pragma unroll
            for (int j = 0; j < 8; ++j) {
                _Float16 hi, lo; fsplit(vv[j], hi, lo);
                hh[j] = hi; ll[j] = lo;
            }
            ah[m] = hh; al[m] = ll;
        }
#pragma unroll
        for (int n = 0; n < 4; ++n) {
            const size_t gb = (size_t)(wc + n * 16 + (lane & 15)) * 64 + k0;
            const f16x8 bh = *reinterpret_cast<const f16x8*>(Chi + gb);
            const f16x8 bl = *reinterpret_cast<const f16x8*>(Clo + gb);
#pragma unroll
            for (int m = 0; m < 4; ++m)
                acc0[m][n] = __builtin_amdgcn_mfma_f32_16x16x32_f16(
                    ah[m], bh, acc0[m][n], 0, 0, 0);
#pragma unroll
            for (int m = 0; m < 4; ++m)
                acc1[m][n] = __builtin_amdgcn_mfma_f32_16x16x32_f16(
                    ah[m], bl, acc1[m][n], 0, 0, 0);
#pragma unroll
            for (int m = 0; m < 4; ++m)
                acc1[m][n] = __builtin_amdgcn_mfma_f32_16x16x32_f16(
                    al[m], bh, acc1[m][n], 0, 0, 0);
        }
    }

#pragma unroll
    for (int m = 0; m < 4; ++m)
#pragma unroll
        for (int n = 0; n < 4; ++n) {
            const int col = wc + n * 16 + (lane & 15);
            const float cf = ccf[col];
#pragma unroll
            for (int q = 0; q < 4; ++q) {
                const int rl = wr + m * 16 + (lane >> 4) * 4 + q;
                float dot = acc0[m][n][q] + SPLIT_SCALE * acc1[m][n][q];
                acc0[m][n][q] = (xxf[rl] - 2.0f * dot) + cf;
            }
        }

    float bvr[4][4]; int bir[4][4];
#pragma unroll
    for (int m = 0; m < 4; ++m)
#pragma unroll
        for (int q = 0; q < 4; ++q) {
            float bv = 3.4e38f; int bi = 0;
#pragma unroll
            for (int n = 0; n < 4; ++n) {
                const int col = wc + n * 16 + (lane & 15);
                const float v = acc0[m][n][q];
                if (v < bv || (v == bv && col < bi)) { bv = v; bi = col; }
            }
            bvr[m][q] = bv; bir[m][q] = bi;
        }
#pragma unroll
    for (int mask = 1; mask < 16; mask <<= 1) {
#pragma unroll
        for (int m = 0; m < 4; ++m)
#pragma unroll
            for (int q = 0; q < 4; ++q) {
                float ov = __shfl_xor(bvr[m][q], mask);
                int   oi = __shfl_xor(bir[m][q], mask);
                if (ov < bvr[m][q] || (ov == bvr[m][q] && oi < bir[m][q])) {
                    bvr[m][q] = ov; bir[m][q] = oi;
                }
            }
    }
    if ((lane & 15) == 0) {
#pragma unroll
        for (int m = 0; m < 4; ++m)
#pragma unroll
            for (int q = 0; q < 4; ++q) {
                const int rl = wr + m * 16 + (lane >> 4) * 4 + q;
                redv[w & 3][rl] = bvr[m][q];
                redi[w & 3][rl] = bir[m][q];
            }
    }
    __syncthreads();

    if (tid < 128) {
        float bv = 3.4e38f; int bi = 0;
#pragma unroll
        for (int nw = 0; nw < 4; ++nw) {
            float v = redv[nw][tid];
            if (v < bv) { bv = v; bi = redi[nw][tid]; }
        }
        bv1s[tid] = bv; bis[tid] = bi;
    }
    __syncthreads();

#pragma unroll
    for (int m = 0; m < 4; ++m)
#pragma unroll
        for (int q = 0; q < 4; ++q) {
            const int rl = wr + m * 16 + (lane >> 4) * 4 + q;
            const float thr = bv1s[rl] + VQ_EPS;
#pragma unroll
            for (int n = 0; n < 4; ++n) {
                const int col = wc + n * 16 + (lane & 15);
                if (acc0[m][n][q] <= thr) {
                    int s = atomicAdd(&ncand[rl], 1);
                    if (s < 16) cand[rl][s] = col;
                    else        fullflag[rl] = 1;
                }
            }
        }
    __syncthreads();

    if (tid < 128) {
        const int nc_ = ncand[tid] < 16 ? ncand[tid] : 16;
        if (nc_ > 1 && !fullflag[tid]) {
            const float4* z4p = reinterpret_cast<const float4*>(Z + (size_t)(bm + tid) * 64);
            const double xx = xxd[tid];
            double best = 1.0e300; int bi = 256;
            for (int s = 0; s < nc_; ++s) {
                const int e = cand[tid][s];
                const float4* c4p = reinterpret_cast<const float4*>(CB + (size_t)e * 64);
                double dot = 0.0;
#pragma unroll
                for (int v = 0; v < 16; ++v) {
                    float4 zf = z4p[v], cf4 = c4p[v];
                    dot = fma((double)zf.x, (double)cf4.x, dot);
                    dot = fma((double)zf.y, (double)cf4.y, dot);
                    dot = fma((double)zf.z, (double)cf4.z, dot);
                    dot = fma((double)zf.w, (double)cf4.w, dot);
                }
                double d2x = (xx - 2.0 * dot) + ccd[e];
                if (d2x < best || (d2x == best && e < bi)) { best = d2x; bi = e; }
            }
            bis[tid] = bi;
        }
        if (fullflag[tid]) {
            int s = atomicAdd(&nflag, 1);
            flaglist[s] = tid;
        }
    }
    __syncthreads();

    for (int fi = w; fi < nflag; fi += 8) {
        const int rl = flaglist[fi];
        const float* zr = Z + (size_t)(bm + rl) * 64;
        const double xx = xxd[rl];
        double best = 1.0e300; int bi = 256;
#pragma unroll
        for (int j = 0; j < 4; ++j) {
            const int e = lane + j * 64;
            const float* c = CB + (size_t)e * 64;
            double dot = 0.0;
#pragma unroll
            for (int d = 0; d < 64; ++d)
                dot = fma((double)zr[d], (double)c[d], dot);
            double d2x = (xx - 2.0 * dot) + ccd[e];
            if (d2x < best || (d2x == best && e < bi)) { best = d2x; bi = e; }
        }
#pragma unroll
        for (int mask = 1; mask < 64; mask <<= 1) {
            double ov = __shfl_xor(best, mask);
            int    oi = __shfl_xor(bi, mask);
            if (ov < best || (ov == best && oi < bi)) { best = ov; bi = oi; }
        }
        if (lane == 0) bis[rl] = bi;
    }
    __syncthreads();

    {
        const int row  = tid >> 2;
        const int part = tid & 3;
        const int bi   = bis[row];
        const float4* src = reinterpret_cast<const float4*>(CB + (size_t)bi * 64) + part * 4;
        float* dst = OUT + (size_t)(bm + row) * 64 + part * 16;
        unsigned short* dq = ZQB + (size_t)(bm + row) * 64 + part * 16;
#pragma unroll
        for (int v = 0; v < 4; ++v) {
            float4 f = src[v];
            *reinterpret_cast<float4*>(dst + v * 4) = f;
            ushort4 qb = { f2bf(f.x), f2bf(f.y), f2bf(f.z), f2bf(f.w) };
            *reinterpret_cast<ushort4*>(dq + v * 4) = qb;
        }
    }
}

// ---------------------------------------------------------------------------
// small prep kernels
// ---------------------------------------------------------------------------
__global__ __launch_bounds__(256)
void transpose_bf16(const float* __restrict__ W, unsigned short* __restrict__ Wt,
                    int K, int N)
{
    int idx = blockIdx.x * 256 + threadIdx.x;
    if (idx >= K * N) return;
    int n = idx / K, k = idx % K;
    Wt[idx] = f2bf(W[(size_t)k * N + n]);
}

__global__ __launch_bounds__(256)
void transpose_split_f16(const float* __restrict__ W,
                         _Float16* __restrict__ Whi, _Float16* __restrict__ Wlo,
                         int K, int N)
{
    int idx = blockIdx.x * 256 + threadIdx.x;
    if (idx >= K * N) return;
    int n = idx / K, k = idx % K;
    _Float16 hi, lo; fsplit(W[(size_t)k * N + n], hi, lo);
    Whi[idx] = hi; Wlo[idx] = lo;
}

// X -> hi/lo planes, 8 elems/thread (vectorized, BW-bound)
__global__ __launch_bounds__(256)
void split_vec_f16(const float* __restrict__ src,
                   _Float16* __restrict__ hi, _Float16* __restrict__ lo, long n8)
{
    long i = (long)blockIdx.x * 256 + threadIdx.x;
    if (i >= n8) return;
    float4 a = *reinterpret_cast<const float4*>(&src[i * 8]);
    float4 b = *reinterpret_cast<const float4*>(&src[i * 8 + 4]);
    _Float16 h[8], l[8];
    fsplit(a.x, h[0], l[0]); fsplit(a.y, h[1], l[1]);
    fsplit(a.z, h[2], l[2]); fsplit(a.w, h[3], l[3]);
    fsplit(b.x, h[4], l[4]); fsplit(b.y, h[5], l[5]);
    fsplit(b.z, h[6], l[6]); fsplit(b.w, h[7], l[7]);
    *reinterpret_cast<float4*>(&hi[i * 8]) = *reinterpret_cast<float4*>(h);
    *reinterpret_cast<float4*>(&lo[i * 8]) = *reinterpret_cast<float4*>(l);
}

__global__ __launch_bounds__(256)
void split_flat_f16(const float* __restrict__ src,
                    _Float16* __restrict__ hi, _Float16* __restrict__ lo, int n)
{
    int i = blockIdx.x * 256 + threadIdx.x;
    if (i >= n) return;
    _Float16 h, l; fsplit(src[i], h, l);
    hi[i] = h; lo[i] = l;
}

// ---------------------------------------------------------------------------
extern "C" void kernel_launch(void* const* d_in, const int* in_sizes, int n_in,
                              void* d_out, int out_size, void* d_ws, size_t ws_size,
                              hipStream_t stream)
{
    const float* X  = (const float*)d_in[0];
    const float* W0 = (const float*)d_in[1];
    const float* b0 = (const float*)d_in[2];
    const float* W1 = (const float*)d_in[3];
    const float* b1 = (const float*)d_in[4];
    const float* W2 = (const float*)d_in[5];
    const float* b2 = (const float*)d_in[6];
    const float* CB = (const float*)d_in[7];
    const float* W3 = (const float*)d_in[8];
    const float* b3 = (const float*)d_in[9];
    const float* W4 = (const float*)d_in[10];
    const float* b4 = (const float*)d_in[11];
    const float* W5 = (const float*)d_in[12];
    const float* b5 = (const float*)d_in[13];

    const int D_in = 256, H = 512, R = 64, S = 512, NA = 8;
    const int Mtot = in_sizes[0] / D_in;          // 131072

    float* recon = (float*)d_out;
    float* ze    = recon + (size_t)(Mtot / NA) * S;
    float* remb  = ze + (size_t)Mtot * R;

    // ---- workspace: fixed weight planes + FULL-M zqb ----
    char* p = (char*)d_ws;
    _Float16* W0hi = (_Float16*)p;  p += (size_t)H * D_in * 2;
    _Float16* W0lo = (_Float16*)p;  p += (size_t)H * D_in * 2;
    _Float16* W1hi = (_Float16*)p;  p += (size_t)H * H * 2;
    _Float16* W1lo = (_Float16*)p;  p += (size_t)H * H * 2;
    _Float16* W2thi = (_Float16*)p; p += (size_t)R * H * 2;
    _Float16* W2tlo = (_Float16*)p; p += (size_t)R * H * 2;
    _Float16* CBhi = (_Float16*)p;  p += (size_t)256 * R * 2;
    _Float16* CBlo = (_Float16*)p;  p += (size_t)256 * R * 2;
    unsigned short* W3t = (unsigned short*)p;  p += (size_t)H * R * 2;
    unsigned short* W4t = (unsigned short*)p;  p += (size_t)H * (NA * H) * 2;
    unsigned short* W5t = (unsigned short*)p;  p += (size_t)S * H * 2;
    unsigned short* zqb = (unsigned short*)p;  p += (size_t)Mtot * R * 2;   // 16.8 MB
    size_t fixed = (size_t)(p - (char*)d_ws);
    fixed = (fixed + 255) & ~(size_t)255;

    // big region: encoder phase uses [regionA (X then h1) | regionB (h0)],
    // each rpc*2048 B; decoder phase reuses regionB as rec1b, regionA as rec2b.
    int nc = 1;
    while (nc < 128) {
        size_t rpcT = (size_t)Mtot / nc;
        if (fixed + rpcT * 4096 + 1024 <= ws_size) break;
        nc *= 2;
    }
    const int rpc = Mtot / nc;
    char* regionA = (char*)d_ws + fixed;                 // rpc*2048
    char* regionB = regionA + (size_t)rpc * 2048;        // rpc*2048

    // encoder-phase views
    _Float16* Xhi  = (_Float16*)regionA;                         // rpc*512 B
    _Float16* Xlo  = Xhi + (size_t)rpc * D_in;                   // rpc*512 B
    _Float16* h1hi = (_Float16*)regionA;                         // overwrites X (dead)
    _Float16* h1lo = h1hi + (size_t)rpc * H;
    _Float16* h0hi = (_Float16*)regionB;
    _Float16* h0lo = h0hi + (size_t)rpc * H;

    // decoder chunking: rec1b needs Mdec*1024 B <= regionB (rpc*2048)
    int dc = (nc >= 2) ? nc / 2 : 1;
    const int Mdec = Mtot / dc;
    unsigned short* rec1b = (unsigned short*)regionB;            // Mdec*1024 B
    unsigned short* rec2b = (unsigned short*)regionA;            // Mdec*128 B

    // ---- one-time weight prep ----
    transpose_split_f16<<<(H * D_in + 255) / 256, 256, 0, stream>>>(W0, W0hi, W0lo, D_in, H);
    transpose_split_f16<<<(H * H + 255) / 256, 256, 0, stream>>>(W1, W1hi, W1lo, H, H);
    transpose_split_f16<<<(H * R + 255) / 256, 256, 0, stream>>>(W2, W2thi, W2tlo, H, R);
    split_flat_f16<<<(256 * R + 255) / 256, 256, 0, stream>>>(CB, CBhi, CBlo, 256 * R);
    transpose_bf16<<<(H * R + 255) / 256, 256, 0, stream>>>(W3, W3t, R, H);
    transpose_bf16<<<(H * NA * H + 255) / 256, 256, 0, stream>>>(W4, W4t, NA * H, H);
    transpose_bf16<<<(S * H + 255) / 256, 256, 0, stream>>>(W5, W5t, H, S);

    // ---- encoder + VQ per chunk (zqb written for full M) ----
    for (int r0 = 0; r0 < Mtot; r0 += rpc) {
        split_vec_f16<<<(int)(((long)rpc * D_in / 8 + 255) / 256), 256, 0, stream>>>(
            X + (size_t)r0 * D_in, Xhi, Xlo, (long)rpc * D_in / 8);
        gemm_split7<256><<<dim3(H / 64, rpc / 128), 256, 0, stream>>>(
            Xhi, Xlo, W0hi, W0lo, b0, h0hi, h0lo, rpc, H);
        gemm_split7<512><<<dim3(H / 64, rpc / 128), 256, 0, stream>>>(
            h0hi, h0lo, W1hi, W1lo, b1, h1hi, h1lo, rpc, H);
        gemm_ze_mfma<<<rpc / 128, 256, 0, stream>>>(
            h1hi, h1lo, W2thi, W2tlo, b2, ze + (size_t)r0 * R, rpc);
        vq_mfma<<<rpc / 128, 512, 0, stream>>>(
            ze + (size_t)r0 * R, CB, CBhi, CBlo,
            remb + (size_t)r0 * R, zqb + (size_t)r0 * R);
    }

    // ---- decoder over full M (or Mdec chunks), bigger grids ----
    for (int r0 = 0; r0 < Mtot; r0 += Mdec) {
        const int M6 = Mdec / NA;
        gemm_bt7<true, true><<<dim3(H / 128, Mdec / 128), 256, 0, stream>>>(
            zqb + (size_t)r0 * R, W3t, b3, rec1b, Mdec, H, R);
        gemm_bt7<true, true><<<dim3(H / 128, M6 / 128), 256, 0, stream>>>(
            rec1b, W4t, b4, rec2b, M6, H, NA * H);
        gemm_bt7<false, false><<<dim3(S / 128, M6 / 128), 256, 0, stream>>>(
            rec2b, W5t, b5, recon + (size_t)(r0 / NA) * S, M6, S, H);
    }
}